// Round 1
// baseline (1171.357 us; speedup 1.0000x reference)
//
#include <hip/hip_runtime.h>
#include <hip/hip_bf16.h>

#define LN_EPS 1e-5f

// MFMA fragment types (per guide §3, compile-verified pattern on gfx950)
typedef __attribute__((ext_vector_type(8))) short bf16x8;   // 8 bf16 = 4 VGPRs
typedef __attribute__((ext_vector_type(4))) float f32x4;    // 4 fp32 acc

__device__ __forceinline__ unsigned short f2bf(float f) {
    unsigned int u = __float_as_uint(f);
    u += 0x7fffu + ((u >> 16) & 1u);   // round-to-nearest-even
    return (unsigned short)(u >> 16);
}
__device__ __forceinline__ float bf2f(unsigned short s) {
    return __uint_as_float(((unsigned int)s) << 16);
}

// ---------------- constants ----------------
// N=65536, D=256, Hd=1024, E=8
#define DD   256
#define HD   1024
#define NE   8
#define TN   64      // nodes per block
#define LDH  264     // LDS row stride in bf16 elems (256 + 8 pad -> 2-way-free b128 reads)

// ---------------- weight packing ----------------
// pw1[e][g][n][j] = bf16(W1[e][g*8+j][n]),  g in [0,32), n in [0,1024), j in [0,8)
__global__ void pack_w1(const float* __restrict__ W1, unsigned short* __restrict__ pw1) {
    int t = blockIdx.x * 256 + threadIdx.x;          // [0, 262144)
    int n = t & 1023;
    int g = (t >> 10) & 31;
    int e = t >> 15;
    const float* src = W1 + ((size_t)(e * 256 + g * 8)) * 1024 + n;
    union { unsigned short s[8]; int4 v; } u;
#pragma unroll
    for (int j = 0; j < 8; ++j) u.s[j] = f2bf(src[(size_t)j * 1024]);
    *(int4*)(pw1 + (size_t)t * 8) = u.v;
}

// pw2[e][g][n][j] = bf16(W2[e][g*8+j][n]),  g in [0,128), n in [0,256), j in [0,8)
__global__ void pack_w2(const float* __restrict__ W2, unsigned short* __restrict__ pw2) {
    int t = blockIdx.x * 256 + threadIdx.x;          // [0, 262144)
    int n = t & 255;
    int g = (t >> 8) & 127;
    int e = t >> 15;
    const float* src = W2 + ((size_t)(e * 1024 + g * 8)) * 256 + n;
    union { unsigned short s[8]; int4 v; } u;
#pragma unroll
    for (int j = 0; j < 8; ++j) u.s[j] = f2bf(src[(size_t)j * 256]);
    *(int4*)(pw2 + (size_t)t * 8) = u.v;
}

// ---------------- fused MoE block ----------------
__global__ __launch_bounds__(256, 2)
void moe_main(const float* __restrict__ H, const float* __restrict__ gate_w,
              const float* __restrict__ gate_b, const float* __restrict__ b1,
              const float* __restrict__ b2, const float* __restrict__ ln_g,
              const float* __restrict__ ln_b,
              const unsigned short* __restrict__ pw1,
              const unsigned short* __restrict__ pw2,
              float* __restrict__ out)
{
    __shared__ unsigned short sH[TN * LDH];     // 33792 B  H tile (bf16)
    __shared__ unsigned short sHC[TN * LDH];    // 33792 B  h chunk (bf16)
    __shared__ float sGW[DD * NE];              // 8192 B   gate_w
    __shared__ float sWts[TN * NE];             // 2048 B   logits -> softmax weights
    __shared__ float sRed[TN * 8];              // 2048 B   per-wave LN partials
    __shared__ float sMu[TN * 2];               // 512 B    mu, rstd

    const int tid  = threadIdx.x;
    const int lane = tid & 63;
    const int wave = tid >> 6;
    const int l15  = lane & 15;
    const int quad = lane >> 4;
    const int node0 = blockIdx.x * TN;
    const int ncol  = wave * 64;                // this wave's output-col base (both stages)

    // ---- stage H tile (fp32 -> bf16 LDS) + gate_w ----
    for (int i = tid; i < TN * (DD / 4); i += 256) {
        int row = i >> 6, c4 = i & 63;
        const float4 v = ((const float4*)(H + (size_t)(node0 + row) * DD))[c4];
        unsigned short* dst = &sH[row * LDH + c4 * 4];
        dst[0] = f2bf(v.x); dst[1] = f2bf(v.y); dst[2] = f2bf(v.z); dst[3] = f2bf(v.w);
    }
    for (int i = tid; i < DD * NE; i += 256) sGW[i] = gate_w[i];
    __syncthreads();

    // ---- gating logits (each thread: 2 of 512 (n,e) pairs) ----
    for (int p = tid; p < TN * NE; p += 256) {
        int n = p >> 3, e = p & 7;
        float acc = gate_b[e];
        for (int d = 0; d < DD; ++d)
            acc += bf2f(sH[n * LDH + d]) * sGW[d * NE + e];
        sWts[p] = acc;
    }
    __syncthreads();
    if (tid < TN) {
        float lg[8], mx = -1e30f;
#pragma unroll
        for (int e = 0; e < 8; ++e) { lg[e] = sWts[tid * 8 + e]; mx = fmaxf(mx, lg[e]); }
        float s = 0.f;
#pragma unroll
        for (int e = 0; e < 8; ++e) { lg[e] = __expf(lg[e] - mx); s += lg[e]; }
        float inv = 1.0f / s;
#pragma unroll
        for (int e = 0; e < 8; ++e) sWts[tid * 8 + e] = lg[e] * inv;
    }
    __syncthreads();

    // ---- main compute ----
    f32x4 oacc[4][4];
#pragma unroll
    for (int i = 0; i < 4; ++i)
#pragma unroll
        for (int j = 0; j < 4; ++j) oacc[i][j] = (f32x4){0.f, 0.f, 0.f, 0.f};

    for (int e = 0; e < NE; ++e) {
        // gating weight for this lane's 16 node slots
        float wreg[4][4];
#pragma unroll
        for (int im = 0; im < 4; ++im)
#pragma unroll
            for (int r = 0; r < 4; ++r)
                wreg[im][r] = sWts[(im * 16 + quad * 4 + r) * 8 + e];

        const unsigned short* pw1e = pw1 + (size_t)e * (32 * HD * 8);
        const unsigned short* pw2e = pw2 + (size_t)e * (128 * DD * 8);

        for (int c = 0; c < 4; ++c) {           // Hd chunks of 256
            // ---- stage 1: hc = relu(Htile @ W1[:,chunk] + b1) * w ----
            f32x4 acc1[4][4];
#pragma unroll
            for (int i = 0; i < 4; ++i)
#pragma unroll
                for (int j = 0; j < 4; ++j) acc1[i][j] = (f32x4){0.f, 0.f, 0.f, 0.f};

#pragma unroll
            for (int kk = 0; kk < 8; ++kk) {    // K = 256 over D
                bf16x8 a[4], b[4];
#pragma unroll
                for (int im = 0; im < 4; ++im)
                    a[im] = *(const bf16x8*)&sH[(im * 16 + l15) * LDH + kk * 32 + quad * 8];
#pragma unroll
                for (int in = 0; in < 4; ++in) {
                    int g = kk * 4 + quad;
                    int n = c * 256 + ncol + in * 16 + l15;
                    b[in] = *(const bf16x8*)&pw1e[((size_t)g * HD + n) * 8];
                }
#pragma unroll
                for (int im = 0; im < 4; ++im)
#pragma unroll
                    for (int in = 0; in < 4; ++in)
                        acc1[im][in] = __builtin_amdgcn_mfma_f32_16x16x32_bf16(
                            a[im], b[in], acc1[im][in], 0, 0, 0);
            }
            // epilogue -> sHC (bf16)
#pragma unroll
            for (int in = 0; in < 4; ++in) {
                int hdl = ncol + in * 16 + l15;             // chunk-local hd col
                float b1v = b1[e * HD + c * 256 + hdl];
#pragma unroll
                for (int im = 0; im < 4; ++im)
#pragma unroll
                    for (int r = 0; r < 4; ++r) {
                        float v = acc1[im][in][r] + b1v;
                        v = fmaxf(v, 0.f) * wreg[im][r];
                        sHC[(im * 16 + quad * 4 + r) * LDH + hdl] = f2bf(v);
                    }
            }
            __syncthreads();
            // ---- stage 2: oacc += hc @ W2[chunk,:] ----
#pragma unroll
            for (int kk = 0; kk < 8; ++kk) {    // K = 256 over chunk
                bf16x8 a[4], b[4];
#pragma unroll
                for (int im = 0; im < 4; ++im)
                    a[im] = *(const bf16x8*)&sHC[(im * 16 + l15) * LDH + kk * 32 + quad * 8];
#pragma unroll
                for (int in = 0; in < 4; ++in) {
                    int g = c * 32 + kk * 4 + quad;
                    int n = ncol + in * 16 + l15;
                    b[in] = *(const bf16x8*)&pw2e[((size_t)g * DD + n) * 8];
                }
#pragma unroll
                for (int im = 0; im < 4; ++im)
#pragma unroll
                    for (int in = 0; in < 4; ++in)
                        oacc[im][in] = __builtin_amdgcn_mfma_f32_16x16x32_bf16(
                            a[im], b[in], oacc[im][in], 0, 0, 0);
            }
            __syncthreads();
        }
    }

    // ---- epilogue: x = H + moe_out + sum_e w*b2 ; LayerNorm ----
    float b2v[4][8];
#pragma unroll
    for (int in = 0; in < 4; ++in)
#pragma unroll
        for (int e2 = 0; e2 < 8; ++e2)
            b2v[in][e2] = b2[e2 * DD + ncol + in * 16 + l15];

#pragma unroll
    for (int im = 0; im < 4; ++im)
#pragma unroll
        for (int r = 0; r < 4; ++r) {
            int node = im * 16 + quad * 4 + r;
            float wv[8];
#pragma unroll
            for (int e2 = 0; e2 < 8; ++e2) wv[e2] = sWts[node * 8 + e2];
#pragma unroll
            for (int in = 0; in < 4; ++in) {
                int dcol = ncol + in * 16 + l15;
                float x = oacc[im][in][r] + H[(size_t)(node0 + node) * DD + dcol];
#pragma unroll
                for (int e2 = 0; e2 < 8; ++e2) x += wv[e2] * b2v[in][e2];
                oacc[im][in][r] = x;
            }
        }

    // per-node sums (each node lives in one 16-lane quad-group per wave)
#pragma unroll
    for (int im = 0; im < 4; ++im)
#pragma unroll
        for (int r = 0; r < 4; ++r) {
            int node = im * 16 + quad * 4 + r;
            float s = 0.f, s2 = 0.f;
#pragma unroll
            for (int in = 0; in < 4; ++in) { float x = oacc[im][in][r]; s += x; s2 += x * x; }
#pragma unroll
            for (int off = 1; off < 16; off <<= 1) {
                s  += __shfl_xor(s,  off, 64);
                s2 += __shfl_xor(s2, off, 64);
            }
            if (l15 == 0) { sRed[node * 8 + wave * 2] = s; sRed[node * 8 + wave * 2 + 1] = s2; }
        }
    __syncthreads();
    if (tid < TN) {
        float s = 0.f, s2 = 0.f;
        for (int w2 = 0; w2 < 4; ++w2) { s += sRed[tid * 8 + w2 * 2]; s2 += sRed[tid * 8 + w2 * 2 + 1]; }
        float mu  = s * (1.0f / 256.0f);
        float var = s2 * (1.0f / 256.0f) - mu * mu;
        sMu[tid * 2] = mu;
        sMu[tid * 2 + 1] = rsqrtf(var + LN_EPS);
    }
    __syncthreads();

    float lg[4], lb[4];
#pragma unroll
    for (int in = 0; in < 4; ++in) {
        int dcol = ncol + in * 16 + l15;
        lg[in] = ln_g[dcol]; lb[in] = ln_b[dcol];
    }
#pragma unroll
    for (int im = 0; im < 4; ++im)
#pragma unroll
        for (int r = 0; r < 4; ++r) {
            int node = im * 16 + quad * 4 + r;
            float mu = sMu[node * 2], rs = sMu[node * 2 + 1];
#pragma unroll
            for (int in = 0; in < 4; ++in) {
                int dcol = ncol + in * 16 + l15;
                out[(size_t)(node0 + node) * DD + dcol] =
                    (oacc[im][in][r] - mu) * rs * lg[in] + lb[in];
            }
        }
}

extern "C" void kernel_launch(void* const* d_in, const int* in_sizes, int n_in,
                              void* d_out, int out_size, void* d_ws, size_t ws_size,
                              hipStream_t stream) {
    const float* H   = (const float*)d_in[0];
    const float* gw  = (const float*)d_in[1];
    const float* gb  = (const float*)d_in[2];
    const float* W1  = (const float*)d_in[3];
    const float* b1  = (const float*)d_in[4];
    const float* W2  = (const float*)d_in[5];
    const float* b2  = (const float*)d_in[6];
    const float* lng = (const float*)d_in[7];
    const float* lnb = (const float*)d_in[8];
    float* out = (float*)d_out;

    unsigned short* pw1 = (unsigned short*)d_ws;                 // 8*32*1024*8 bf16 = 4 MB
    unsigned short* pw2 = pw1 + (size_t)8 * 32 * 1024 * 8;       // 8*128*256*8 bf16 = 4 MB

    hipLaunchKernelGGL(pack_w1, dim3(1024), dim3(256), 0, stream, W1, pw1);
    hipLaunchKernelGGL(pack_w2, dim3(1024), dim3(256), 0, stream, W2, pw2);
    hipLaunchKernelGGL(moe_main, dim3(65536 / TN), dim3(256), 0, stream,
                       H, gw, gb, b1, b2, lng, lnb, pw1, pw2, out);
}

// Round 2
// 886.685 us; speedup vs baseline: 1.3211x; 1.3211x over previous
//
#include <hip/hip_runtime.h>
#include <hip/hip_bf16.h>

#define LN_EPS 1e-5f

typedef __attribute__((ext_vector_type(8))) short bf16x8;   // 8 bf16 = 4 VGPRs
typedef __attribute__((ext_vector_type(4))) float f32x4;    // 4 fp32 acc

__device__ __forceinline__ unsigned short f2bf(float f) {
    unsigned int u = __float_as_uint(f);
    u += 0x7fffu + ((u >> 16) & 1u);   // RNE
    return (unsigned short)(u >> 16);
}
__device__ __forceinline__ float bf2f(unsigned short s) {
    return __uint_as_float(((unsigned int)s) << 16);
}

// N=65536, D=256, Hd=1024, E=8
#define DD   256
#define HD   1024
#define NE   8
#define TN   64      // nodes per block
#define LDH  264     // LDS row stride (bf16 elems): +8 pad -> 2-way (free) b128 reads

// ---------------- weight packing (fragment-major bf16) ----------------
// pw1[e][g][n][j] = bf16(W1[e][g*8+j][n]),  g<32, n<1024, j<8
__global__ void pack_w1(const float* __restrict__ W1, unsigned short* __restrict__ pw1) {
    int t = blockIdx.x * 256 + threadIdx.x;
    int n = t & 1023, g = (t >> 10) & 31, e = t >> 15;
    const float* src = W1 + ((size_t)(e * 256 + g * 8)) * 1024 + n;
    union { unsigned short s[8]; int4 v; } u;
#pragma unroll
    for (int j = 0; j < 8; ++j) u.s[j] = f2bf(src[(size_t)j * 1024]);
    *(int4*)(pw1 + (size_t)t * 8) = u.v;
}
// pw2[e][g][n][j] = bf16(W2[e][g*8+j][n]),  g<128, n<256, j<8
__global__ void pack_w2(const float* __restrict__ W2, unsigned short* __restrict__ pw2) {
    int t = blockIdx.x * 256 + threadIdx.x;
    int n = t & 255, g = (t >> 8) & 127, e = t >> 15;
    const float* src = W2 + ((size_t)(e * 1024 + g * 8)) * 256 + n;
    union { unsigned short s[8]; int4 v; } u;
#pragma unroll
    for (int j = 0; j < 8; ++j) u.s[j] = f2bf(src[(size_t)j * 256]);
    *(int4*)(pw2 + (size_t)t * 8) = u.v;
}

// ---------------- fused MoE block ----------------
__global__ __launch_bounds__(256, 2)
void moe_main(const float* __restrict__ H, const float* __restrict__ gate_w,
              const float* __restrict__ gate_b, const float* __restrict__ b1,
              const float* __restrict__ b2, const float* __restrict__ ln_g,
              const float* __restrict__ ln_b,
              const unsigned short* __restrict__ pw1,
              const unsigned short* __restrict__ pw2,
              float* __restrict__ out)
{
    __shared__ unsigned short sH[TN * LDH];     // 33792 B
    __shared__ unsigned short sHC[TN * LDH];    // 33792 B
    __shared__ float sGW[DD * NE];              // 8192 B
    __shared__ float sWts[TN * NE];             // 2048 B
    __shared__ float sRed[TN * 8];              // 2048 B
    __shared__ float sMu[TN * 2];               // 512 B

    const int tid  = threadIdx.x;
    const int lane = tid & 63;
    const int wave = tid >> 6;
    const int l15  = lane & 15;
    const int quad = lane >> 4;
    const int node0 = blockIdx.x * TN;
    const int ncol  = wave * 64;     // this wave's hd-col (stage1) / d-col (stage2) base

    // ---- stage H tile (fp32 -> bf16 LDS) + gate_w ----
    for (int i = tid; i < TN * (DD / 4); i += 256) {
        int row = i >> 6, c4 = i & 63;
        const float4 v = ((const float4*)(H + (size_t)(node0 + row) * DD))[c4];
        unsigned short* dst = &sH[row * LDH + c4 * 4];
        dst[0] = f2bf(v.x); dst[1] = f2bf(v.y); dst[2] = f2bf(v.z); dst[3] = f2bf(v.w);
    }
    for (int i = tid; i < DD * NE; i += 256) sGW[i] = gate_w[i];
    __syncthreads();

    // ---- prologue: prime the weight-fragment queue with s=0 stage1 kk=0..3 ----
    // frag addressing (identical for A/B roles): 8 K-contiguous bf16 per lane.
    bf16x8 q[4][4];
    {
        const unsigned short* p1 = pw1 + ((size_t)quad * HD + ncol + l15) * 8; // e=0,c=0
#pragma unroll
        for (int kk = 0; kk < 4; ++kk)
#pragma unroll
            for (int im = 0; im < 4; ++im)
                q[kk][im] = *(const bf16x8*)(p1 + ((size_t)kk * 4 * HD + im * 16) * 8);
    }

    // ---- gating ----
    for (int p = tid; p < TN * NE; p += 256) {
        int n = p >> 3, e = p & 7;
        float acc = gate_b[e];
        for (int d = 0; d < DD; ++d)
            acc += bf2f(sH[n * LDH + d]) * sGW[d * NE + e];
        sWts[p] = acc;
    }
    __syncthreads();
    if (tid < TN) {
        float lg[8], mx = -1e30f;
#pragma unroll
        for (int e = 0; e < 8; ++e) { lg[e] = sWts[tid * 8 + e]; mx = fmaxf(mx, lg[e]); }
        float s = 0.f;
#pragma unroll
        for (int e = 0; e < 8; ++e) { lg[e] = __expf(lg[e] - mx); s += lg[e]; }
        float inv = 1.0f / s;
#pragma unroll
        for (int e = 0; e < 8; ++e) sWts[tid * 8 + e] = lg[e] * inv;
    }
    __syncthreads();

    // ---- main loop: 32 (e,c) iterations, rolling 4-batch weight prefetch ----
    f32x4 oacc[4][4];   // [im=d-tile][in=node-tile], D-layout: d=quad*4+r, node=l15
#pragma unroll
    for (int i = 0; i < 4; ++i)
#pragma unroll
        for (int j = 0; j < 4; ++j) oacc[i][j] = (f32x4){0.f, 0.f, 0.f, 0.f};

#pragma unroll 1
    for (int s = 0; s < 32; ++s) {
        const int e = s >> 2, c = s & 3;
        const int sn = (s + 1) & 31;
        const int en = sn >> 2, cn = sn & 3;

        const unsigned short* p1 = pw1 +
            ((size_t)e * 32 * HD + (size_t)quad * HD + c * 256 + ncol + l15) * 8;
        const unsigned short* p2 = pw2 +
            ((size_t)e * 128 * DD + (size_t)(c * 32 + quad) * DD + ncol + l15) * 8;
        const unsigned short* p1n = pw1 +
            ((size_t)en * 32 * HD + (size_t)quad * HD + cn * 256 + ncol + l15) * 8;

        float wge[4];
#pragma unroll
        for (int in = 0; in < 4; ++in) wge[in] = sWts[(in * 16 + l15) * 8 + e];

        // ---- stage 1: acc1[hd][node] = W1chunk^T @ H^T (transposed GEMM) ----
        f32x4 acc1[4][4];
#pragma unroll
        for (int i = 0; i < 4; ++i)
#pragma unroll
            for (int j = 0; j < 4; ++j) acc1[i][j] = (f32x4){0.f, 0.f, 0.f, 0.f};

#pragma unroll
        for (int kk = 0; kk < 8; ++kk) {
            const int slot = kk & 3;
            bf16x8 act[4], nq[4];
#pragma unroll
            for (int in = 0; in < 4; ++in)
                act[in] = *(const bf16x8*)&sH[(in * 16 + l15) * LDH + kk * 32 + quad * 8];
#pragma unroll
            for (int im = 0; im < 4; ++im)
                nq[im] = (kk < 4)
                    ? *(const bf16x8*)(p1 + ((size_t)(kk + 4) * 4 * HD + im * 16) * 8)
                    : *(const bf16x8*)(p2 + ((size_t)(kk - 4) * 4 * DD + im * 16) * 8);
#pragma unroll
            for (int im = 0; im < 4; ++im)
#pragma unroll
                for (int in = 0; in < 4; ++in)
                    acc1[im][in] = __builtin_amdgcn_mfma_f32_16x16x32_bf16(
                        q[slot][im], act[in], acc1[im][in], 0, 0, 0);
#pragma unroll
            for (int im = 0; im < 4; ++im) q[slot][im] = nq[im];
        }

        // ---- epilogue -> sHC (bf16), hd-contiguous per lane -> ds_write_b64 ----
#pragma unroll
        for (int im = 0; im < 4; ++im) {
            const float4 b1v = *(const float4*)&b1[e * HD + c * 256 + ncol + im * 16 + quad * 4];
#pragma unroll
            for (int in = 0; in < 4; ++in) {
                const float w = wge[in];
                float v0 = fmaxf(acc1[im][in][0] + b1v.x, 0.f) * w;
                float v1 = fmaxf(acc1[im][in][1] + b1v.y, 0.f) * w;
                float v2 = fmaxf(acc1[im][in][2] + b1v.z, 0.f) * w;
                float v3 = fmaxf(acc1[im][in][3] + b1v.w, 0.f) * w;
                unsigned int lo = ((unsigned)f2bf(v1) << 16) | f2bf(v0);
                unsigned int hi = ((unsigned)f2bf(v3) << 16) | f2bf(v2);
                *(uint2*)&sHC[(in * 16 + l15) * LDH + ncol + im * 16 + quad * 4] =
                    make_uint2(lo, hi);
            }
        }
        __syncthreads();

        // ---- stage 2: oacc[d][node] += W2chunk^T @ hc^T ----
#pragma unroll
        for (int kk = 0; kk < 8; ++kk) {
            const int slot = kk & 3;
            bf16x8 act[4], nq[4];
#pragma unroll
            for (int in = 0; in < 4; ++in)
                act[in] = *(const bf16x8*)&sHC[(in * 16 + l15) * LDH + kk * 32 + quad * 8];
#pragma unroll
            for (int im = 0; im < 4; ++im)
                nq[im] = (kk < 4)
                    ? *(const bf16x8*)(p2 + ((size_t)(kk + 4 - 4 + 4) * 4 * DD + im * 16) * 8)
                    : *(const bf16x8*)(p1n + ((size_t)(kk - 4) * 4 * HD + im * 16) * 8);
#pragma unroll
            for (int im = 0; im < 4; ++im)
#pragma unroll
                for (int in = 0; in < 4; ++in)
                    oacc[im][in] = __builtin_amdgcn_mfma_f32_16x16x32_bf16(
                        q[slot][im], act[in], oacc[im][in], 0, 0, 0);
#pragma unroll
            for (int im = 0; im < 4; ++im) q[slot][im] = nq[im];
        }
        __syncthreads();
    }

    // ---- epilogue: x = H + moe_out + sum_e w*b2 ; LayerNorm ----
    float wv[4][8];
#pragma unroll
    for (int in = 0; in < 4; ++in)
#pragma unroll
        for (int e2 = 0; e2 < 8; ++e2) wv[in][e2] = sWts[(in * 16 + l15) * 8 + e2];

    f32x4 wb2[4][4];    // [in][im]
#pragma unroll
    for (int in = 0; in < 4; ++in)
#pragma unroll
        for (int im = 0; im < 4; ++im) wb2[in][im] = (f32x4){0.f, 0.f, 0.f, 0.f};
#pragma unroll
    for (int e2 = 0; e2 < 8; ++e2)
#pragma unroll
        for (int im = 0; im < 4; ++im) {
            const float4 bv = *(const float4*)&b2[e2 * DD + ncol + im * 16 + quad * 4];
#pragma unroll
            for (int in = 0; in < 4; ++in) {
                wb2[in][im][0] += wv[in][e2] * bv.x;
                wb2[in][im][1] += wv[in][e2] * bv.y;
                wb2[in][im][2] += wv[in][e2] * bv.z;
                wb2[in][im][3] += wv[in][e2] * bv.w;
            }
        }

#pragma unroll
    for (int im = 0; im < 4; ++im)
#pragma unroll
        for (int in = 0; in < 4; ++in) {
            const float4 hres = *(const float4*)
                &H[(size_t)(node0 + in * 16 + l15) * DD + ncol + im * 16 + quad * 4];
            oacc[im][in][0] += hres.x + wb2[in][im][0];
            oacc[im][in][1] += hres.y + wb2[in][im][1];
            oacc[im][in][2] += hres.z + wb2[in][im][2];
            oacc[im][in][3] += hres.w + wb2[in][im][3];
        }

    // per-node sums: node = in*16+l15; reduce over quads (lane bits 4,5)
    float sum[4], sum2[4];
#pragma unroll
    for (int in = 0; in < 4; ++in) {
        float s = 0.f, s2 = 0.f;
#pragma unroll
        for (int im = 0; im < 4; ++im)
#pragma unroll
            for (int r = 0; r < 4; ++r) { float x = oacc[im][in][r]; s += x; s2 += x * x; }
        s  += __shfl_xor(s, 16);  s  += __shfl_xor(s, 32);
        s2 += __shfl_xor(s2, 16); s2 += __shfl_xor(s2, 32);
        sum[in] = s; sum2[in] = s2;
    }
    if (quad == 0) {
#pragma unroll
        for (int in = 0; in < 4; ++in) {
            sRed[(in * 16 + l15) * 8 + wave * 2]     = sum[in];
            sRed[(in * 16 + l15) * 8 + wave * 2 + 1] = sum2[in];
        }
    }
    __syncthreads();
    if (tid < TN) {
        float s = 0.f, s2 = 0.f;
#pragma unroll
        for (int w2 = 0; w2 < 4; ++w2) { s += sRed[tid * 8 + w2 * 2]; s2 += sRed[tid * 8 + w2 * 2 + 1]; }
        float mu  = s * (1.0f / 256.0f);
        float var = s2 * (1.0f / 256.0f) - mu * mu;
        sMu[tid * 2] = mu;
        sMu[tid * 2 + 1] = rsqrtf(var + LN_EPS);
    }
    __syncthreads();

#pragma unroll
    for (int im = 0; im < 4; ++im) {
        const float4 lgv = *(const float4*)&ln_g[ncol + im * 16 + quad * 4];
        const float4 lbv = *(const float4*)&ln_b[ncol + im * 16 + quad * 4];
#pragma unroll
        for (int in = 0; in < 4; ++in) {
            const int node = in * 16 + l15;
            const float mu = sMu[node * 2], rs = sMu[node * 2 + 1];
            float4 y;
            y.x = (oacc[im][in][0] - mu) * rs * lgv.x + lbv.x;
            y.y = (oacc[im][in][1] - mu) * rs * lgv.y + lbv.y;
            y.z = (oacc[im][in][2] - mu) * rs * lgv.z + lbv.z;
            y.w = (oacc[im][in][3] - mu) * rs * lgv.w + lbv.w;
            *(float4*)&out[(size_t)(node0 + node) * DD + ncol + im * 16 + quad * 4] = y;
        }
    }
}

extern "C" void kernel_launch(void* const* d_in, const int* in_sizes, int n_in,
                              void* d_out, int out_size, void* d_ws, size_t ws_size,
                              hipStream_t stream) {
    const float* H   = (const float*)d_in[0];
    const float* gw  = (const float*)d_in[1];
    const float* gb  = (const float*)d_in[2];
    const float* W1  = (const float*)d_in[3];
    const float* b1  = (const float*)d_in[4];
    const float* W2  = (const float*)d_in[5];
    const float* b2  = (const float*)d_in[6];
    const float* lng = (const float*)d_in[7];
    const float* lnb = (const float*)d_in[8];
    float* out = (float*)d_out;

    unsigned short* pw1 = (unsigned short*)d_ws;                 // 4 MB
    unsigned short* pw2 = pw1 + (size_t)8 * 32 * 1024 * 8;       // 4 MB

    hipLaunchKernelGGL(pack_w1, dim3(1024), dim3(256), 0, stream, W1, pw1);
    hipLaunchKernelGGL(pack_w2, dim3(1024), dim3(256), 0, stream, W2, pw2);
    hipLaunchKernelGGL(moe_main, dim3(65536 / TN), dim3(256), 0, stream,
                       H, gw, gb, b1, b2, lng, lnb, pw1, pw2, out);
}